// Round 1
// 112.978 us; speedup vs baseline: 1.0287x; 1.0287x over previous
//
#include <hip/hip_runtime.h>
#include <hip/hip_bf16.h>

#define NROWS 4096
#define DMODEL 256
#define NHEADS 8
#define HD 32

typedef __attribute__((ext_vector_type(8))) short short8;
typedef __attribute__((ext_vector_type(4))) float f32x4;

// ---------------- prep: casts (fp32->bf16) + segment bounds ----------------
__global__ __launch_bounds__(256) void prep_kernel(
    const float* __restrict__ slots, const float* __restrict__ w_in,
    const float* __restrict__ w_out, const int* __restrict__ bidx,
    __hip_bfloat16* __restrict__ Abf, __hip_bfloat16* __restrict__ Winb,
    __hip_bfloat16* __restrict__ Woutb, int* __restrict__ segs) {
  const int bid = blockIdx.x;
  const float* src;
  __hip_bfloat16* dst;
  int i;
  if (bid < 1024)      { src = slots; dst = Abf;   i = (bid * 256 + (int)threadIdx.x) * 4; }
  else if (bid < 1216) { src = w_in;  dst = Winb;  i = ((bid - 1024) * 256 + (int)threadIdx.x) * 4; }
  else if (bid < 1280) { src = w_out; dst = Woutb; i = ((bid - 1216) * 256 + (int)threadIdx.x) * 4; }
  else {
    const int r = (bid - 1280) * 256 + threadIdx.x;
    const int b = bidx[r];
    if (r == 0 || bidx[r - 1] != b) segs[b] = r;
    if (r == NROWS - 1 || bidx[r + 1] != b) segs[16 + b] = r + 1;
    return;
  }
  const float4 v = *(const float4*)(src + i);
  __hip_bfloat162 lo, hi;
  lo.x = __float2bfloat16(v.x); lo.y = __float2bfloat16(v.y);
  hi.x = __float2bfloat16(v.z); hi.y = __float2bfloat16(v.w);
  *(__hip_bfloat162*)(dst + i) = lo;
  *(__hip_bfloat162*)(dst + i + 2) = hi;
}

// ---------------- QKV GEMM: barrier-free, direct-from-global frags ---------
// 64x64 tile, 4 waves; wave wv does rows [bm+wv*16, +16) x cols [bn, bn+64).
// A/B frags loaded straight from global (16 B/lane, L1/L2-resident weights).
__global__ __launch_bounds__(256, 4) void gemm_qkv(
    const __hip_bfloat16* __restrict__ A,   // [4096][256]
    const __hip_bfloat16* __restrict__ B,   // [768][256] (w_in bf16)
    const float* __restrict__ bias,         // [768]
    __hip_bfloat16* __restrict__ Qo,        // [H][N][32]
    __hip_bfloat16* __restrict__ Ko,        // [H][N][32]
    __hip_bfloat16* __restrict__ Vo) {      // [H][32][N] (transposed)
  const int wv   = threadIdx.x >> 6;
  const int lane = threadIdx.x & 63;
  const int lo16 = lane & 15;
  const int quad = lane >> 4;
  const int bm = blockIdx.y * 64 + wv * 16;
  const int bn = blockIdx.x * 64;

  f32x4 acc[4] = {};
  #pragma unroll
  for (int k0 = 0; k0 < 256; k0 += 32) {
    const short8 af = *(const short8*)(A + (size_t)(bm + lo16) * 256 + k0 + quad * 8);
    #pragma unroll
    for (int ni = 0; ni < 4; ni++) {
      const short8 bf = *(const short8*)(B + (size_t)(bn + ni * 16 + lo16) * 256 + k0 + quad * 8);
      acc[ni] = __builtin_amdgcn_mfma_f32_16x16x32_bf16(af, bf, acc[ni], 0, 0, 0);
    }
  }
  #pragma unroll
  for (int ni = 0; ni < 4; ni++) {
    const int col = bn + ni * 16 + lo16;
    const int sel = col >> 8;          // 0:Q 1:K 2:V
    const int h = (col & 255) >> 5;
    const int d = col & 31;
    const float bv = bias[col];
    #pragma unroll
    for (int r = 0; r < 4; r++) {
      const int n = bm + quad * 4 + r;
      const __hip_bfloat16 v = __float2bfloat16(acc[ni][r] + bv);
      if (sel == 0)      Qo[((size_t)h * NROWS + n) * HD + d] = v;
      else if (sel == 1) Ko[((size_t)h * NROWS + n) * HD + d] = v;
      else               Vo[((size_t)h * HD + d) * NROWS + n] = v;
    }
  }
}

// ---------------- attention: 4-way split-K flash decoding ------------------
// Swapped-operand QK^T: s = mfma(K, Q) gives S^T, so each lane owns ONE
// q-row (q = lane&15) and 8 k-values -> row max/sum are 7 in-lane ops +
// 2 shuffles (xor16/xor32), instead of 32 ds_swizzles per tile.
// O-rescale alphas (needed in output-row layout) bounce via a 16-float LDS
// array, skipped entirely when no row's max grew (defer-max).
// All exponentials in exp2 domain (scale folded with log2(e)).
__global__ __launch_bounds__(256, 4) void attn_mfma(
    const __hip_bfloat16* __restrict__ Qb,  // [H][N][32]
    const __hip_bfloat16* __restrict__ Kb,  // [H][N][32]
    const __hip_bfloat16* __restrict__ Vt,  // [H][32][N]
    const int* __restrict__ bidx,
    const int* __restrict__ segs,
    __hip_bfloat16* __restrict__ out)       // [N][256] bf16
{
  __shared__ __align__(16) __hip_bfloat16 Plds_all[4][16][40];
  __shared__ __align__(16) float alds_all[4][16];
  __shared__ float mld[4][16], lld[4][16];
  __shared__ float Old[4][16][32];
  const int wv   = threadIdx.x >> 6;
  const int lane = threadIdx.x & 63;
  const int qt   = blockIdx.x >> 3;
  const int h    = blockIdx.x & 7;
  const int r0   = qt * 16;
  const int lo16 = lane & 15;
  const int quad = lane >> 4;
  __hip_bfloat16 (*Plds)[40] = Plds_all[wv];
  float* alds = alds_all[wv];

  // per-lane q-row bounds (this lane's q-row is r0 + lo16)
  const int bq  = bidx[r0 + lo16];
  const int stq = segs[bq];
  const unsigned rng = (unsigned)(segs[16 + bq] - stq);

  const int kstart = segs[bidx[r0]] & ~31;
  const int kend   = segs[16 + bidx[r0 + 15]];
  const int ntiles = (kend - kstart + 31) >> 5;

  const short8 qf = *(const short8*)(Qb + ((size_t)h * NROWS + r0 + lo16) * HD + quad * 8);

  f32x4 o0 = {0.f, 0.f, 0.f, 0.f}, o1 = {0.f, 0.f, 0.f, 0.f};
  float m = -1e30f, l = 0.0f;
  // 1/sqrt(32) * log2(e): softmax carried in exp2 domain
  const float scale2 = 0.17677669529663687f * 1.4426950408889634f;

  for (int t = wv; t < ntiles; t += 4) {
    const int c0 = kstart + t * 32;
    // K rows c0+lo16 / c0+16+lo16 are always < NROWS (c0 <= 4064, 32-aligned)
    const short8 kf0 = *(const short8*)(Kb + ((size_t)h * NROWS + c0 + lo16) * HD + quad * 8);
    const short8 kf1 = *(const short8*)(Kb + ((size_t)h * NROWS + c0 + 16 + lo16) * HD + quad * 8);
    const int vc = c0 + quad * 8;
    const short8 vf0 = *(const short8*)(Vt + ((size_t)h * HD + lo16) * NROWS + vc);
    const short8 vf1 = *(const short8*)(Vt + ((size_t)h * HD + 16 + lo16) * NROWS + vc);

    const f32x4 z = {0.f, 0.f, 0.f, 0.f};
    // swapped operands: S^T. lane holds q = lo16, k = c0 + quad*4 + r (+16)
    f32x4 s0 = __builtin_amdgcn_mfma_f32_16x16x32_bf16(kf0, qf, z, 0, 0, 0);
    f32x4 s1 = __builtin_amdgcn_mfma_f32_16x16x32_bf16(kf1, qf, z, 0, 0, 0);

    const int kb = c0 + quad * 4 - stq;
    float p0v[4], p1v[4];
    float mx = -3e38f;
    #pragma unroll
    for (int r = 0; r < 4; r++) {
      const float sc0 = ((unsigned)(kb + r)      < rng) ? s0[r] * scale2 : -3e38f;
      const float sc1 = ((unsigned)(kb + 16 + r) < rng) ? s1[r] * scale2 : -3e38f;
      p0v[r] = sc0; p1v[r] = sc1;
      mx = fmaxf(mx, fmaxf(sc0, sc1));
    }
    // reduce across the 4 lanes holding this q-row (bits 4,5 of lane id)
    mx = fmaxf(mx, __shfl_xor(mx, 16));
    mx = fmaxf(mx, __shfl_xor(mx, 32));
    const float nm = fmaxf(m, mx);
    float ps = 0.0f;
    #pragma unroll
    for (int r = 0; r < 4; r++) {
      p0v[r] = __builtin_amdgcn_exp2f(p0v[r] - nm);
      p1v[r] = __builtin_amdgcn_exp2f(p1v[r] - nm);
      ps += p0v[r] + p1v[r];
    }
    ps += __shfl_xor(ps, 16);
    ps += __shfl_xor(ps, 32);

    const float alpha = __builtin_amdgcn_exp2f(m - nm);
    l = l * alpha + ps;
    if (!__all(nm == m)) {   // some row's max grew: rescale O (row layout)
      if (quad == 0) alds[lo16] = alpha;
      const f32x4 av = *(const f32x4*)&alds[quad * 4];  // av[r] = alpha(row quad*4+r)
      #pragma unroll
      for (int r = 0; r < 4; r++) { o0[r] *= av[r]; o1[r] *= av[r]; }
    }
    m = nm;

    // P^T(lane) -> P(LDS): lane writes row q=lo16, k = quad*4+{0..3} (+16)
    {
      __hip_bfloat162* pw0 = (__hip_bfloat162*)&Plds[lo16][quad * 4];
      __hip_bfloat162* pw1 = (__hip_bfloat162*)&Plds[lo16][16 + quad * 4];
      __hip_bfloat162 a, b;
      a.x = __float2bfloat16(p0v[0]); a.y = __float2bfloat16(p0v[1]);
      b.x = __float2bfloat16(p0v[2]); b.y = __float2bfloat16(p0v[3]);
      pw0[0] = a; pw0[1] = b;
      a.x = __float2bfloat16(p1v[0]); a.y = __float2bfloat16(p1v[1]);
      b.x = __float2bfloat16(p1v[2]); b.y = __float2bfloat16(p1v[3]);
      pw1[0] = a; pw1[1] = b;
    }
    const short8 pf = *(const short8*)&Plds[lo16][quad * 8];
    o0 = __builtin_amdgcn_mfma_f32_16x16x32_bf16(pf, vf0, o0, 0, 0, 0);
    o1 = __builtin_amdgcn_mfma_f32_16x16x32_bf16(pf, vf1, o1, 0, 0, 0);
  }

  // ---- publish per-wave state ----
  #pragma unroll
  for (int r = 0; r < 4; r++) {
    const int row = quad * 4 + r;
    Old[wv][row][lo16]      = o0[r];
    Old[wv][row][lo16 + 16] = o1[r];
  }
  if (quad == 0) { mld[wv][lo16] = m; lld[wv][lo16] = l; }
  __syncthreads();

  // ---- merge: thread -> (row = tid>>4, cols {c, c+16}) ----
  const int row = threadIdx.x >> 4;
  const int c   = threadIdx.x & 15;
  float M = fmaxf(fmaxf(mld[0][row], mld[1][row]),
                  fmaxf(mld[2][row], mld[3][row]));
  float L = 0.f, O0 = 0.f, O1 = 0.f;
  #pragma unroll
  for (int w = 0; w < 4; w++) {
    const float e = __builtin_amdgcn_exp2f(mld[w][row] - M);
    L  += e * lld[w][row];
    O0 += e * Old[w][row][c];
    O1 += e * Old[w][row][c + 16];
  }
  const float inv = 1.0f / L;
  const int grow = r0 + row;
  out[(size_t)grow * DMODEL + h * HD + c]      = __float2bfloat16(O0 * inv);
  out[(size_t)grow * DMODEL + h * HD + 16 + c] = __float2bfloat16(O1 * inv);
}

// ---------------- out-proj + residual + LayerNorm (fused) ------------------
// 16x256 tile (row-complete), 4 waves; wave wv does cols [wv*64, +64).
// Direct-from-global frags (w_out bf16 is 128 KB, L2-resident).
__global__ __launch_bounds__(256, 4) void gemm_out_ln(
    const __hip_bfloat16* __restrict__ A,   // attnb [4096][256]
    const __hip_bfloat16* __restrict__ B,   // w_out bf16 [256][256]
    const float* __restrict__ bias,         // b_out
    const float* __restrict__ x,            // slots fp32 (residual)
    const float* __restrict__ gamma, const float* __restrict__ beta,
    float* __restrict__ out) {
  __shared__ float red1[16][4], red2[16][4];
  const int wv   = threadIdx.x >> 6;
  const int lane = threadIdx.x & 63;
  const int lo16 = lane & 15;
  const int quad = lane >> 4;
  const int r0 = blockIdx.x * 16;
  const int wn = wv * 64;

  f32x4 acc[4] = {};
  #pragma unroll
  for (int k0 = 0; k0 < 256; k0 += 32) {
    const short8 af = *(const short8*)(A + (size_t)(r0 + lo16) * 256 + k0 + quad * 8);
    #pragma unroll
    for (int ni = 0; ni < 4; ni++) {
      const short8 bf = *(const short8*)(B + (size_t)(wn + ni * 16 + lo16) * 256 + k0 + quad * 8);
      acc[ni] = __builtin_amdgcn_mfma_f32_16x16x32_bf16(af, bf, acc[ni], 0, 0, 0);
    }
  }

  // val = delta + bias + residual; per-row partial sums across this wave
  float val[4][4];
  float s1[4] = {}, s2[4] = {};
  #pragma unroll
  for (int ni = 0; ni < 4; ni++) {
    const int col = wn + ni * 16 + lo16;
    const float bv = bias[col];
    #pragma unroll
    for (int r = 0; r < 4; r++) {
      const int row = r0 + quad * 4 + r;
      const float v = acc[ni][r] + bv + x[(size_t)row * DMODEL + col];
      val[ni][r] = v;
      s1[r] += v;
      s2[r] += v * v;
    }
  }
  #pragma unroll
  for (int r = 0; r < 4; r++) {
    #pragma unroll
    for (int off = 1; off < 16; off <<= 1) {
      s1[r] += __shfl_xor(s1[r], off);
      s2[r] += __shfl_xor(s2[r], off);
    }
    if (lo16 == 0) { red1[quad * 4 + r][wv] = s1[r]; red2[quad * 4 + r][wv] = s2[r]; }
  }
  __syncthreads();
  #pragma unroll
  for (int r = 0; r < 4; r++) {
    const int lrow = quad * 4 + r;
    const float mean = (red1[lrow][0] + red1[lrow][1] + red1[lrow][2] + red1[lrow][3]) * (1.0f / DMODEL);
    const float ex2  = (red2[lrow][0] + red2[lrow][1] + red2[lrow][2] + red2[lrow][3]) * (1.0f / DMODEL);
    const float rstd = rsqrtf(fmaxf(ex2 - mean * mean, 0.0f) + 1e-5f);
    const int row = r0 + lrow;
    #pragma unroll
    for (int ni = 0; ni < 4; ni++) {
      const int col = wn + ni * 16 + lo16;
      out[(size_t)row * DMODEL + col] =
          (val[ni][r] - mean) * rstd * gamma[col] + beta[col];
    }
  }
}

extern "C" void kernel_launch(void* const* d_in, const int* in_sizes, int n_in,
                              void* d_out, int out_size, void* d_ws, size_t ws_size,
                              hipStream_t stream) {
  const float* slots  = (const float*)d_in[0];
  const int*   bidx   = (const int*)  d_in[1];
  const float* w_in   = (const float*)d_in[2];
  const float* b_in   = (const float*)d_in[3];
  const float* w_out  = (const float*)d_in[4];
  const float* b_out  = (const float*)d_in[5];
  const float* ln_g   = (const float*)d_in[6];
  const float* ln_b   = (const float*)d_in[7];
  float* out = (float*)d_out;

  char* ws = (char*)d_ws;
  __hip_bfloat16* Abf   = (__hip_bfloat16*)(ws);                 // 2 MB
  __hip_bfloat16* Qb    = (__hip_bfloat16*)(ws + (2u  << 20));   // 2 MB
  __hip_bfloat16* Kb    = (__hip_bfloat16*)(ws + (4u  << 20));   // 2 MB
  __hip_bfloat16* Vt    = (__hip_bfloat16*)(ws + (6u  << 20));   // 2 MB
  __hip_bfloat16* attnb = (__hip_bfloat16*)(ws + (8u  << 20));   // 2 MB
  __hip_bfloat16* Winb  = (__hip_bfloat16*)(ws + (10u << 20));   // 384 KB
  __hip_bfloat16* Woutb = (__hip_bfloat16*)(ws + (10u << 20) + (512u << 10)); // 128 KB
  int*            segs  = (int*)           (ws + (11u << 20));   // 32 ints

  // 0) fused casts + segment bounds
  prep_kernel<<<1296, 256, 0, stream>>>(slots, w_in, w_out, bidx,
                                        Abf, Winb, Woutb, segs);
  // 1) QKV projection -> scattered Q/K/Vt (bf16), 768 blocks
  {
    dim3 grid(768 / 64, NROWS / 64);
    gemm_qkv<<<grid, 256, 0, stream>>>(Abf, Winb, b_in, Qb, Kb, Vt);
  }
  // 2) split-K flash attention, one block per (q-tile, head)
  attn_mfma<<<(NROWS / 16) * NHEADS, 256, 0, stream>>>(Qb, Kb, Vt, bidx,
                                                       segs, attnb);
  // 3) out-proj + residual + LayerNorm, 256 blocks
  gemm_out_ln<<<NROWS / 16, 256, 0, stream>>>(attnb, Woutb, b_out, slots,
                                              ln_g, ln_b, out);
}